// Round 3
// baseline (758.771 us; speedup 1.0000x reference)
//
#include <hip/hip_runtime.h>

// x: (1, 64, 32, 64, 64) f32   -> NN-upsample 2x2x2 -> (1,64,64,128,128)
// y = einsum('ncdhw,oc->nodhw', u, W) + b
// z: (1, 64, 68, 132, 132) f32 -> center crop (off 2,2,2) -> (1,64,64,128,128)
// out = concat([y, zc], axis=1): (1, 128, 64, 128, 128) f32

#define XC   64
#define XD   32
#define XH   64
#define XW   64
#define XPL  (XD * XH * XW)                  // 131072 floats per input channel

#define OD   64
#define OH   128
#define OW   128
#define OCH_STRIDE ((size_t)OD * OH * OW)    // 1,048,576 floats per out channel

#define ZD   68
#define ZH   132
#define ZW   132

typedef float f32x2 __attribute__((ext_vector_type(2)));
typedef float f32x4 __attribute__((ext_vector_type(4)));

// ---------------------------------------------------------------------------
// Kernel 1: upsample + 1x1x1 conv, o-split 2 via blockIdx.y.
// One thread per x position (d,h,w); wave = full w-row (w == lane).
// Per o: 64-FMA dot (2 partial chains), 2 shfls rearrange into the
// replicated row pattern [a,a,b,b,...]; one wave store covers rows
// (2d,2h) and (2d,2h+1) = 1 KiB contiguous. Nontemporal (out not re-read).
// ---------------------------------------------------------------------------
__global__ __launch_bounds__(256) void upconv_kernel(
    const float* __restrict__ x, const float* __restrict__ W,
    const float* __restrict__ b, float* __restrict__ out) {
  const int pos  = blockIdx.x * 256 + threadIdx.x;   // 0 .. 131071
  const int lane = threadIdx.x & 63;                 // == w
  const int h = (pos >> 6) & 63;
  const int d = pos >> 12;

  float xv[XC];
#pragma unroll
  for (int c = 0; c < XC; ++c) xv[c] = x[(size_t)c * XPL + pos];

  const int j    = lane & 31;     // float4 index within output row
  const int rsel = lane >> 5;     // 0 -> row 2h, 1 -> row 2h+1
  const size_t base0 = ((size_t)(2 * d) * OH + (2 * h + rsel)) * OW + 4 * j;
  const size_t planeStride = (size_t)OH * OW;        // to plane 2d+1

  const int o_begin = blockIdx.y * 32;
  float* p = out + (size_t)o_begin * OCH_STRIDE + base0;
#pragma unroll 4
  for (int oi = 0; oi < 32; ++oi) {
    const int o = o_begin + oi;
    float s0 = 0.f, s1 = 0.f;
#pragma unroll
    for (int c = 0; c < 32; ++c) {
      s0 += W[o * XC + c]      * xv[c];        // uniform -> scalar loads
      s1 += W[o * XC + 32 + c] * xv[32 + c];
    }
    const float acc = b[o] + s0 + s1;
    const float a  = __shfl(acc, 2 * j);
    const float bb = __shfl(acc, 2 * j + 1);
    f32x4 v = {a, a, bb, bb};
    __builtin_nontemporal_store(v, (f32x4*)(p));               // plane 2d
    __builtin_nontemporal_store(v, (f32x4*)(p + planeStride)); // plane 2d+1
    p += OCH_STRIDE;
  }
}

// ---------------------------------------------------------------------------
// Kernel 2: center-crop z -> out channels 64..127.
// Grid-stride: 2048 blocks x 256 thr, 32 compile-time iterations/thread,
// 16 B (4 w-floats) per unit. Src rows 8B-aligned -> 2x float2 loads;
// dst 16B-aligned -> nontemporal float4 store.
// ---------------------------------------------------------------------------
#define CC_BLOCKS 2048
#define CC_STRIDE (CC_BLOCKS * 256u)          // 524288 units/round
#define CC_TOTAL  (64u * 64u * 128u * 32u)    // 16,777,216 units

__global__ __launch_bounds__(256) void cropcat_kernel(
    const float* __restrict__ z, float* __restrict__ out) {
  const unsigned u0 = blockIdx.x * 256u + threadIdx.x;
#pragma unroll 4
  for (unsigned k = 0; k < CC_TOTAL / CC_STRIDE; ++k) {   // 32 iterations
    const unsigned u = u0 + k * CC_STRIDE;
    const int w4 = (u & 31) << 2;
    const int h  = (u >> 5) & 127;
    const int d  = (u >> 12) & 63;
    const int c  = u >> 18;

    const float* src =
        z + ((size_t)((c * ZD + d + 2) * ZH + (h + 2))) * ZW + (w4 + 2);
    const f32x2 a  = *(const f32x2*)(src);
    const f32x2 bb = *(const f32x2*)(src + 2);

    float* dst = out + (size_t)(64 + c) * OCH_STRIDE + ((size_t)d * OH + h) * OW + w4;
    f32x4 v = {a.x, a.y, bb.x, bb.y};
    __builtin_nontemporal_store(v, (f32x4*)dst);
  }
}

extern "C" void kernel_launch(void* const* d_in, const int* in_sizes, int n_in,
                              void* d_out, int out_size, void* d_ws, size_t ws_size,
                              hipStream_t stream) {
  const float* x = (const float*)d_in[0];
  const float* z = (const float*)d_in[1];
  const float* W = (const float*)d_in[2];
  const float* b = (const float*)d_in[3];
  float* out = (float*)d_out;

  dim3 grid1(512, 2);                       // 131072 positions, o-split 2
  upconv_kernel<<<grid1, 256, 0, stream>>>(x, W, b, out);

  cropcat_kernel<<<CC_BLOCKS, 256, 0, stream>>>(z, out);
}

// Round 4
// 744.909 us; speedup vs baseline: 1.0186x; 1.0186x over previous
//
#include <hip/hip_runtime.h>

// x: (1, 64, 32, 64, 64) f32   -> NN-upsample 2x2x2 -> (1,64,64,128,128)
// y = einsum('ncdhw,oc->nodhw', u, W) + b
// z: (1, 64, 68, 132, 132) f32 -> center crop (off 2,2,2) -> (1,64,64,128,128)
// out = concat([y, zc], axis=1): (1, 128, 64, 128, 128) f32

#define XC   64
#define XD   32
#define XH   64
#define XW   64
#define XPL  (XD * XH * XW)                  // 131072 floats per input channel

#define OD   64
#define OH   128
#define OW   128
#define OCH_STRIDE ((size_t)OD * OH * OW)    // 1,048,576 floats per out channel

#define ZD   68
#define ZH   132
#define ZW   132

typedef float f32x2 __attribute__((ext_vector_type(2)));
typedef float f32x4 __attribute__((ext_vector_type(4)));

// ---------------------------------------------------------------------------
// Kernel 1: upsample + 1x1x1 conv, o-split 2 via blockIdx.y (4 blocks/CU).
// One thread per x position; wave spans the full w-row (w == lane).
// Per o: 64-FMA dot (2 chains), 2 shfls form the [a,a,b,b,...] replicated
// pattern; each wave store = 1 KiB contiguous float4 covering rows
// (2d,2h) and (2d,2h+1); repeated for plane 2d+1.
// ---------------------------------------------------------------------------
__global__ __launch_bounds__(256) void upconv_kernel(
    const float* __restrict__ x, const float* __restrict__ W,
    const float* __restrict__ b, float* __restrict__ out) {
  const int pos  = blockIdx.x * 256 + threadIdx.x;   // 0 .. 131071
  const int lane = threadIdx.x & 63;                 // == w
  const int h = (pos >> 6) & 63;
  const int d = pos >> 12;

  float xv[XC];
#pragma unroll
  for (int c = 0; c < XC; ++c) xv[c] = x[(size_t)c * XPL + pos];

  const int j    = lane & 31;     // float4 index within output row
  const int rsel = lane >> 5;     // 0 -> row 2h, 1 -> row 2h+1
  const size_t base0 = ((size_t)(2 * d) * OH + (2 * h + rsel)) * OW + 4 * j;
  const size_t planeStride = (size_t)OH * OW;        // to plane 2d+1

  const int o_begin = blockIdx.y * 32;
  float* p = out + (size_t)o_begin * OCH_STRIDE + base0;
#pragma unroll 4
  for (int oi = 0; oi < 32; ++oi) {
    const int o = o_begin + oi;
    float s0 = 0.f, s1 = 0.f;
#pragma unroll
    for (int c = 0; c < 32; ++c) {
      s0 += W[o * XC + c]      * xv[c];        // wave-uniform -> scalar loads
      s1 += W[o * XC + 32 + c] * xv[32 + c];
    }
    const float acc = b[o] + s0 + s1;
    const float a  = __shfl(acc, 2 * j);
    const float bb = __shfl(acc, 2 * j + 1);
    const f32x4 v = {a, a, bb, bb};
    *(f32x4*)(p)               = v;            // plane 2d   (1 KiB/wave)
    *(f32x4*)(p + planeStride) = v;            // plane 2d+1
    p += OCH_STRIDE;
  }
}

// ---------------------------------------------------------------------------
// Kernel 2: center-crop z -> out channels 64..127.
// 32 B (8 w-floats) per thread-unit; 2048 blocks x 256 thr, 16 compile-time
// grid-stride iterations. Src rows 8B-aligned -> 4x float2 loads; dst
// 16B-aligned -> 2x float4 stores.
// ---------------------------------------------------------------------------
#define CC_BLOCKS 2048
#define CC_STRIDE (CC_BLOCKS * 256u)          // 524288 units/round
#define CC_TOTAL  (64u * 64u * 128u * 16u)    // 8,388,608 units (32 B each)

__global__ __launch_bounds__(256) void cropcat_kernel(
    const float* __restrict__ z, float* __restrict__ out) {
  const unsigned u0 = blockIdx.x * 256u + threadIdx.x;
#pragma unroll
  for (unsigned k = 0; k < CC_TOTAL / CC_STRIDE; ++k) {   // 16 iterations
    const unsigned u = u0 + k * CC_STRIDE;
    const int w8 = (u & 15) << 3;
    const int h  = (u >> 4) & 127;
    const int d  = (u >> 11) & 63;
    const int c  = u >> 17;

    const float* src =
        z + ((size_t)((c * ZD + d + 2) * ZH + (h + 2))) * ZW + (w8 + 2);
    const f32x2 a0 = *(const f32x2*)(src);
    const f32x2 a1 = *(const f32x2*)(src + 2);
    const f32x2 a2 = *(const f32x2*)(src + 4);
    const f32x2 a3 = *(const f32x2*)(src + 6);

    float* dst = out + (size_t)(64 + c) * OCH_STRIDE + ((size_t)d * OH + h) * OW + w8;
    const f32x4 v0 = {a0.x, a0.y, a1.x, a1.y};
    const f32x4 v1 = {a2.x, a2.y, a3.x, a3.y};
    *(f32x4*)(dst)     = v0;
    *(f32x4*)(dst + 4) = v1;
  }
}

extern "C" void kernel_launch(void* const* d_in, const int* in_sizes, int n_in,
                              void* d_out, int out_size, void* d_ws, size_t ws_size,
                              hipStream_t stream) {
  const float* x = (const float*)d_in[0];
  const float* z = (const float*)d_in[1];
  const float* W = (const float*)d_in[2];
  const float* b = (const float*)d_in[3];
  float* out = (float*)d_out;

  dim3 grid1(512, 2);                       // 131072 positions, o-split 2
  upconv_kernel<<<grid1, 256, 0, stream>>>(x, W, b, out);

  cropcat_kernel<<<CC_BLOCKS, 256, 0, stream>>>(z, out);
}